// Round 6
// baseline (31.269 us; speedup 1.0000x reference)
//
#include <hip/hip_runtime.h>
#include <math.h>

// STP forward as affine recurrence on r = imu/mu:
//   d[n] = a + (x[n-1]+x[n])/2
//   r[n] = exp(-d[n]) * (r[n-1] + x[n-1]/2) + x[n]/2
// td[n] = (r[n] > 0) ? 1 - r[n] : 1 ; chunk(500)-boundary carry clamp r>0?r:1.
// Carry into a chunk is attenuated by exp(-(500a+trapz)) <= ~1e-14, so
// r_raw[c-1] is a pure function of chunk c-1's inputs -> each block
// recomputes chunk c-1 locally; no cross-block dependency, single kernel.
//
// Segment composition in the integrating-factor (log2) domain:
//   Sz_n = Sz_{n-1} + d_n*log2e          (f64, adds only - no exp poly)
//   h_k  = 0.5*x_k * 2^{Sz_k}            (2^Sz via HW v_exp_f32 + f64 eps-fix)
//   T_n  = T_{n-1} + h_{n-1} + h_n       (f64 accumulation)
//   segment map: r_L = (r_0 + T_L) / 2^{Sz_L}
// Cross-segment scan composes (E=2^{Sz_L} [f64 exp2], rho=T_L) in LDS.
// Max Sz_chunk*ln2 ~ 254 -> 2^Sz <= ~1e110, safely inside f64 range.

#define TDIM 50000
#define UDIM 16
#define NCH 100
#define SEG 20      // 25-step sub-segments per chunk
#define SLEN 25
#define NSEQ 128    // B*U

#define LOG2E 1.4426950408889634
#define LN2   0.6931471805599453

__device__ __forceinline__ float clean(float v) { return (v != v) ? 0.0f : v; }

// Compose one 25-element segment: returns E = 2^{Sz_L} (f64) and rho = T_L.
// p points at the segment's first element; has_prev selects the boundary x.
__device__ __forceinline__ void seg_compose(
    const float* __restrict__ p, bool has_prev, float ui, double al2,
    double& Eseg, double& rho)
{
    float xpf = has_prev ? ui * clean(p[-UDIM]) : 0.0f;
    double xhp = (double)(0.5f * xpf);   // 0.5*x_{n-1} (exact f32 halving)
    double hp  = xhp;                    // h_0 = 0.5*x_0 * 2^0
    double Sz = 0.0, T = 0.0;
#pragma unroll 5
    for (int t = 0; t < SLEN; ++t) {
        const float ts = clean(p[(size_t)t * UDIM]);
        const float x  = ui * ts;
        const double xh = (double)(0.5f * x);
        Sz += fma(xhp + xh, LOG2E, al2);          // += (a+(xp+x)/2)*log2e
        const float  zf = (float)Sz;
        const float  Ef = __builtin_amdgcn_exp2f(zf);   // HW v_exp_f32
        const double dl = (Sz - (double)zf) * LN2;      // cast-residual fix
        const double Ed = (double)Ef;
        const double E  = fma(Ed, dl, Ed);              // 2^{Sz}, rel ~1e-7
        const double h  = xh * E;
        T += hp + h;
        hp = h; xhp = xh;
    }
    Eseg = exp2(Sz);    // f64 libm, once per segment
    rho  = T;
}

__global__ __launch_bounds__(320, 6) void stp_one(
    const float* __restrict__ inp, const float* __restrict__ uu,
    const float* __restrict__ tauv, float* __restrict__ out)
{
    const int c = blockIdx.x >> 3;           // chunk 0..99
    const int b = blockIdx.x & 7;            // batch 0..7 (== XCD id)
    const int s = threadIdx.x >> 4;          // seg-in-chunk 0..19
    const int u = threadIdx.x & 15;
    const int cm1 = (c > 0) ? c - 1 : 0;     // c==0: L-chain junk, discarded
    const int n0R = c   * 500 + s * SLEN;
    const int n0L = cm1 * 500 + s * SLEN;

    // Replicate reference f32 -> f64 promotion exactly:
    const float ui   = (fabsf(uu[u]) / 100.0f) * 100.0f;
    const float taui = fmaxf(fabsf(tauv[u]), 0.02001f) * 100.0f;
    const float af   = 1.0f / taui;          // f32 divide (as in reference)
    const double al2 = (double)af * LOG2E;   // a*log2e

    const float* pL = inp + ((size_t)b * TDIM + n0L) * UDIM + u;
    const float* pR = inp + ((size_t)b * TDIM + n0R) * UDIM + u;

    __shared__ double sEL[SEG][16], sRL[SEG][16];
    __shared__ double sER[SEG][16], sRR[SEG][16];

    double E1, r1, E2, r2;
    seg_compose(pL, n0L != 0, ui, al2, E1, r1);   // prev-chunk segment
    seg_compose(pR, n0R != 0, ui, al2, E2, r2);   // own segment
    sEL[s][u] = E1; sRL[s][u] = r1;
    sER[s][u] = E2; sRR[s][u] = r2;
    __syncthreads();

    // raw end of chunk c-1 from entry 0: rp = (sum rho_j*Eacc_j) / Eacc_20
    double Esof = 1.0, Tacc = 0.0;
#pragma unroll
    for (int j = 0; j < SEG; ++j) {
        Tacc = fma(sRL[j][u], Esof, Tacc);
        Esof *= sEL[j][u];
    }
    const double rp = Tacc / Esof;

    // exclusive prefix over own chunk's segs 0..s-1
    double Esof2 = 1.0, Tacc2 = 0.0;
    for (int j = 0; j < s; ++j) {
        Tacc2 = fma(sRR[j][u], Esof2, Tacc2);
        Esof2 *= sER[j][u];
    }

    double carry, tdp_d;
    if (c > 0) {
        carry = (rp > 0.0) ? rp : 1.0;       // clamped carry
        tdp_d = (rp > 0.0) ? 1.0 - rp : 1.0; // td from RAW end of prev chunk
    } else {
        carry = 0.0;                          // chunk 0: imu0 = 0
        tdp_d = 1.0;                          // out[0] uses pad value 1.0
    }
    const double r_in = (carry + Tacc2) / Esof2;
    if (s > 0) tdp_d = (r_in > 0.0) ? 1.0 - r_in : 1.0;

    // ---- phase 2: f32 replay (input L1/L2-hot) ----
    float* o = out + ((size_t)b * TDIM + n0R) * UDIM + u;
    float xpf = (n0R != 0) ? ui * clean(pR[-UDIM]) : 0.0f;
    float r   = (float)r_in;
    float tdp = (float)tdp_d;
#pragma unroll 5
    for (int t = 0; t < SLEN; ++t) {
        const float ts = clean(pR[(size_t)t * UDIM]);
        const float x  = ui * ts;
        const float d  = af + (xpf + x) * 0.5f;
        const float e  = __expf(-d);
        r = e * (r + xpf * 0.5f) + x * 0.5f;
        o[(size_t)t * UDIM] = ts * tdp;      // out[n] = tstim[n]*td[n-1]
        tdp = (r > 0.0f) ? 1.0f - r : 1.0f;
        xpf = x;
    }
}

extern "C" void kernel_launch(void* const* d_in, const int* in_sizes, int n_in,
                              void* d_out, int out_size, void* d_ws, size_t ws_size,
                              hipStream_t stream) {
    const float* inp  = (const float*)d_in[0];
    const float* uu   = (const float*)d_in[1];
    const float* tauv = (const float*)d_in[2];
    float* out = (float*)d_out;

    stp_one<<<dim3(NCH * 8), dim3(320), 0, stream>>>(inp, uu, tauv, out);
}